// Round 2
// baseline (1249.349 us; speedup 1.0000x reference)
//
#include <hip/hip_runtime.h>

typedef unsigned short u16;
typedef __attribute__((ext_vector_type(8))) short short8;   // 8 bf16 (4 VGPRs) MFMA A/B frag
typedef __attribute__((ext_vector_type(4))) short shortx4;  // 4 bf16 (8B)
typedef __attribute__((ext_vector_type(4))) float floatx4;  // MFMA C/D frag

#define S_ 2048
#define D_ 1024
#define H_ 16
#define DH_ 64

__device__ __forceinline__ float bf2f(u16 x) {
    union { unsigned int u; float f; } v; v.u = ((unsigned int)x) << 16; return v.f;
}
__device__ __forceinline__ u16 f2bf(float f) {
    unsigned int u = __float_as_uint(f);
    return (u16)((u + 0x7fffu + ((u >> 16) & 1u)) >> 16);  // RNE
}
__device__ __forceinline__ float rdlane(float v, int lane) {
    return __int_as_float(__builtin_amdgcn_readlane(__float_as_int(v), lane));
}

// ---------------- Wt[n][k] = bf16(W[k][n]), W fp32 1024x1024 ----------------
__global__ __launch_bounds__(256) void transpose_w(const float* __restrict__ W, u16* __restrict__ Wt) {
    __shared__ u16 tile[32][33];
    const int tx = threadIdx.x, ty = threadIdx.y;
    const int n0 = blockIdx.x * 32, k0 = blockIdx.y * 32;
#pragma unroll
    for (int r = 0; r < 4; ++r) {
        int k = ty + r * 8;
        tile[k][tx] = f2bf(W[(size_t)(k0 + k) * D_ + n0 + tx]);
    }
    __syncthreads();
#pragma unroll
    for (int r = 0; r < 4; ++r) {
        int n = ty + r * 8;
        Wt[(size_t)(n0 + n) * D_ + k0 + tx] = tile[tx][n];
    }
}

// ------- Kt[bh][d][s] = K[b*S+s][h*64+d]  (per-head K transpose, bf16) -------
__global__ __launch_bounds__(256) void transpose_k(const u16* __restrict__ K, u16* __restrict__ Kt) {
    __shared__ u16 tile[64 * 65];
    const int t = threadIdx.x;
    const int bh = blockIdx.y, b = bh >> 4, h = bh & 15;
    const int s0 = blockIdx.x << 6;
#pragma unroll
    for (int i = 0; i < 16; ++i) {
        int idx = t + (i << 8);
        int s = idx >> 6, d = idx & 63;
        tile[s * 65 + d] = K[(size_t)(b * S_ + s0 + s) * D_ + h * DH_ + d];
    }
    __syncthreads();
#pragma unroll
    for (int i = 0; i < 16; ++i) {
        int idx = t + (i << 8);
        int d = idx >> 6, s = idx & 63;
        Kt[((size_t)bh * DH_ + d) * S_ + s0 + s] = tile[s * 65 + d];
    }
}

// ------- C[M,N] = A[M,K] @ Bt[N,K]^T + bias; fp32 acc, bf16 MFMA -------
// A: fp32 (AF32) or bf16. C: fp32 (OUTF32) or bf16. Bt/internal: bf16.
// 128x128 tile, BK=32, 4 waves each own a 64x64 quadrant (4x4 MFMA tiles).
template <bool AF32, bool OUTF32>
__global__ __launch_bounds__(256) void gemm_nt_bias(const void* __restrict__ Ap, const u16* __restrict__ Bt,
                                                    const float* __restrict__ bias, void* __restrict__ Cp,
                                                    int M, int N, int K) {
    __shared__ __align__(16) u16 As[128 * 40];  // stride 40 bf16 = 80B (16B-aligned rows)
    __shared__ __align__(16) u16 Bs[128 * 40];
    const int t = threadIdx.x;
    const int m0 = blockIdx.y * 128, n0 = blockIdx.x * 128;
    const int w = t >> 6, lane = t & 63;
    const int lr = lane & 15, lg = lane >> 4;
    const int wm = (w >> 1) * 64, wn = (w & 1) * 64;
    floatx4 acc[4][4] = {};

    for (int k0 = 0; k0 < K; k0 += 32) {
#pragma unroll
        for (int c = 0; c < 2; ++c) {  // stage B: 128 rows x 32 k (bf16, 16B/thread/c)
            int idx = t + c * 256;
            int row = idx >> 2, k8 = (idx & 3) << 3;
            *(uint4*)&Bs[row * 40 + k8] = *(const uint4*)&Bt[(size_t)(n0 + row) * K + k0 + k8];
        }
        if (AF32) {
            const float* A = (const float*)Ap;
#pragma unroll
            for (int c = 0; c < 4; ++c) {  // stage A: fp32 load, bf16 pack
                int idx = t + c * 256;
                int row = idx >> 3, k4 = (idx & 7) << 2;
                float4 v = *(const float4*)&A[(size_t)(m0 + row) * K + k0 + k4];
                shortx4 hv;
                hv[0] = (short)f2bf(v.x); hv[1] = (short)f2bf(v.y);
                hv[2] = (short)f2bf(v.z); hv[3] = (short)f2bf(v.w);
                *(shortx4*)&As[row * 40 + k4] = hv;
            }
        } else {
            const u16* A = (const u16*)Ap;
#pragma unroll
            for (int c = 0; c < 2; ++c) {
                int idx = t + c * 256;
                int row = idx >> 2, k8 = (idx & 3) << 3;
                *(uint4*)&As[row * 40 + k8] = *(const uint4*)&A[(size_t)(m0 + row) * K + k0 + k8];
            }
        }
        __syncthreads();
        short8 af[4], bfr[4];
#pragma unroll
        for (int i = 0; i < 4; ++i) af[i]  = *(const short8*)&As[(wm + i * 16 + lr) * 40 + lg * 8];
#pragma unroll
        for (int j = 0; j < 4; ++j) bfr[j] = *(const short8*)&Bs[(wn + j * 16 + lr) * 40 + lg * 8];
#pragma unroll
        for (int i = 0; i < 4; ++i)
#pragma unroll
            for (int j = 0; j < 4; ++j)
                acc[i][j] = __builtin_amdgcn_mfma_f32_16x16x32_bf16(af[i], bfr[j], acc[i][j], 0, 0, 0);
        __syncthreads();
    }

#pragma unroll
    for (int j = 0; j < 4; ++j) {
        int col = n0 + wn + j * 16 + lr;
        float bv = bias[col];
#pragma unroll
        for (int i = 0; i < 4; ++i) {
            int rb = m0 + wm + i * 16 + lg * 4;
#pragma unroll
            for (int ii = 0; ii < 4; ++ii) {
                float val = acc[i][j][ii] + bv;
                if (OUTF32) ((float*)Cp)[(size_t)(rb + ii) * N + col] = val;
                else        ((u16*)Cp)[(size_t)(rb + ii) * N + col] = f2bf(val);
            }
        }
    }
}

// ---------------- flash attention: 16 q/block, LDS-staged K/V tiles ----------------
__device__ __forceinline__ float wave_max(float v) {
#pragma unroll
    for (int off = 32; off; off >>= 1) v = fmaxf(v, __shfl_xor(v, off));
    return v;
}
__device__ __forceinline__ float wave_sum(float v) {
#pragma unroll
    for (int off = 32; off; off >>= 1) v += __shfl_xor(v, off);
    return v;
}

__global__ __launch_bounds__(256) void attn_flash(const u16* __restrict__ Q, const u16* __restrict__ Kt,
                                                  const u16* __restrict__ V, u16* __restrict__ O) {
    __shared__ __align__(16) u16 Ks[64 * 64];  // [d][key]
    __shared__ __align__(16) u16 Vs[64 * 64];  // [key][d]
    const int t = threadIdx.x, w = t >> 6, lane = t & 63;
    const int bh = blockIdx.y, b = bh >> 4, h = bh & 15;
    const int q0 = blockIdx.x * 16;
    const int qw = q0 + w * 4;  // this wave's 4 query rows: qw..qw+3

    float qv[4], m[4], l[4], o[4], p[4];
#pragma unroll
    for (int r = 0; r < 4; ++r) {
        qv[r] = bf2f(Q[(size_t)(b * S_ + qw + r) * D_ + h * DH_ + lane]) * 0.125f;  // fold 1/sqrt(64)
        m[r] = -1e30f; l[r] = 0.f; o[r] = 0.f;
    }

    const u16* KtB = Kt + (size_t)bh * DH_ * S_;           // [64][S]
    const u16* VB  = V + (size_t)b * S_ * D_ + h * DH_;    // row stride D_

    const int nkb = (q0 >> 6) + 1;  // q0..q0+15 share the same last 64-block
    for (int kb = 0; kb < nkb; ++kb) {
        const int K0 = kb << 6;
#pragma unroll
        for (int c = 0; c < 2; ++c) {  // stage 64x64 K-tile + V-tile (8 KB each)
            int idx = t + c * 256;
            int rr = idx >> 3, c8 = (idx & 7) << 3;
            *(uint4*)&Ks[rr * 64 + c8] = *(const uint4*)&KtB[(size_t)rr * S_ + K0 + c8];
            *(uint4*)&Vs[rr * 64 + c8] = *(const uint4*)&VB[(size_t)(K0 + rr) * D_ + c8];
        }
        __syncthreads();

        float s[4] = {0.f, 0.f, 0.f, 0.f};
#pragma unroll 16
        for (int d = 0; d < 64; ++d) {
            float kd = bf2f(Ks[d * 64 + lane]);  // key = lane
#pragma unroll
            for (int r = 0; r < 4; ++r) s[r] += rdlane(qv[r], d) * kd;
        }
        if (kb == nkb - 1) {  // causal mask only possible in the last block
#pragma unroll
            for (int r = 0; r < 4; ++r) s[r] = (K0 + lane <= qw + r) ? s[r] : -1e30f;
        }
#pragma unroll
        for (int r = 0; r < 4; ++r) {
            float mn = fmaxf(m[r], wave_max(s[r]));
            float alpha = __expf(m[r] - mn);
            p[r] = __expf(s[r] - mn);
            l[r] = l[r] * alpha + wave_sum(p[r]);
            o[r] *= alpha;
            m[r] = mn;
        }
#pragma unroll 16
        for (int k2 = 0; k2 < 64; ++k2) {
            float vv = bf2f(Vs[k2 * 64 + lane]);  // d = lane
#pragma unroll
            for (int r = 0; r < 4; ++r) o[r] += rdlane(p[r], k2) * vv;
        }
        __syncthreads();
    }
#pragma unroll
    for (int r = 0; r < 4; ++r)
        O[(size_t)(b * S_ + qw + r) * D_ + h * DH_ + lane] = f2bf(o[r] / l[r]);
}

extern "C" void kernel_launch(void* const* d_in, const int* in_sizes, int n_in,
                              void* d_out, int out_size, void* d_ws, size_t ws_size,
                              hipStream_t stream) {
    (void)in_sizes; (void)n_in; (void)out_size; (void)ws_size;
    const float* x  = (const float*)d_in[0];
    const float* Wq = (const float*)d_in[1];
    const float* bq = (const float*)d_in[2];
    const float* Wk = (const float*)d_in[3];
    const float* bk = (const float*)d_in[4];
    const float* Wv = (const float*)d_in[5];
    const float* bv = (const float*)d_in[6];
    const float* Wo = (const float*)d_in[7];
    const float* bo = (const float*)d_in[8];

    // ws layout (u16 elems): 4x Wt (1M) | Q (4M) | K (4M) | V (4M) | Kt (4M) | attn (4M) = 48 MB
    u16* ws  = (u16*)d_ws;
    u16* Wtq = ws + (size_t)0 * (1 << 20);
    u16* Wtk = ws + (size_t)1 * (1 << 20);
    u16* Wtv = ws + (size_t)2 * (1 << 20);
    u16* Wto = ws + (size_t)3 * (1 << 20);
    u16* Qm  = ws + (size_t)4 * (1 << 20);
    u16* Km  = ws + (size_t)8 * (1 << 20);
    u16* Vm  = ws + (size_t)12 * (1 << 20);
    u16* Ktm = ws + (size_t)16 * (1 << 20);
    u16* Am  = ws + (size_t)20 * (1 << 20);

    dim3 tw_grid(32, 32), tw_blk(32, 8);
    transpose_w<<<tw_grid, tw_blk, 0, stream>>>(Wq, Wtq);
    transpose_w<<<tw_grid, tw_blk, 0, stream>>>(Wk, Wtk);
    transpose_w<<<tw_grid, tw_blk, 0, stream>>>(Wv, Wtv);
    transpose_w<<<tw_grid, tw_blk, 0, stream>>>(Wo, Wto);

    dim3 g_grid(1024 / 128, 4096 / 128);  // (N/128, M/128)
    gemm_nt_bias<true, false><<<g_grid, 256, 0, stream>>>(x, Wtq, bq, Qm, 4096, 1024, 1024);
    gemm_nt_bias<true, false><<<g_grid, 256, 0, stream>>>(x, Wtk, bk, Km, 4096, 1024, 1024);
    gemm_nt_bias<true, false><<<g_grid, 256, 0, stream>>>(x, Wtv, bv, Vm, 4096, 1024, 1024);

    transpose_k<<<dim3(32, 32), 256, 0, stream>>>(Km, Ktm);

    attn_flash<<<dim3(S_ / 16, 32), 256, 0, stream>>>(Qm, Ktm, Vm, Am);

    gemm_nt_bias<false, true><<<g_grid, 256, 0, stream>>>(Am, Wto, bo, d_out, 4096, 1024, 1024);
}

// Round 3
// 332.825 us; speedup vs baseline: 3.7538x; 3.7538x over previous
//
#include <hip/hip_runtime.h>

typedef unsigned short u16;
typedef __attribute__((ext_vector_type(8))) short short8;   // 8 bf16 (4 VGPRs) MFMA A/B frag
typedef __attribute__((ext_vector_type(4))) short shortx4;  // 4 bf16 (8B)
typedef __attribute__((ext_vector_type(4))) float floatx4;  // MFMA C/D frag

#define S_ 2048
#define D_ 1024
#define H_ 16
#define DH_ 64

__device__ __forceinline__ float bf2f(u16 x) {
    union { unsigned int u; float f; } v; v.u = ((unsigned int)x) << 16; return v.f;
}
__device__ __forceinline__ u16 f2bf(float f) {
    unsigned int u = __float_as_uint(f);
    return (u16)((u + 0x7fffu + ((u >> 16) & 1u)) >> 16);  // RNE
}

// ---------------- Wt[n][k] = bf16(W[k][n]), W fp32 1024x1024 ----------------
__global__ __launch_bounds__(256) void transpose_w(const float* __restrict__ W, u16* __restrict__ Wt) {
    __shared__ u16 tile[32][33];
    const int tx = threadIdx.x, ty = threadIdx.y;
    const int n0 = blockIdx.x * 32, k0 = blockIdx.y * 32;
#pragma unroll
    for (int r = 0; r < 4; ++r) {
        int k = ty + r * 8;
        tile[k][tx] = f2bf(W[(size_t)(k0 + k) * D_ + n0 + tx]);
    }
    __syncthreads();
#pragma unroll
    for (int r = 0; r < 4; ++r) {
        int n = ty + r * 8;
        Wt[(size_t)(n0 + n) * D_ + k0 + tx] = tile[tx][n];
    }
}

// ------- Xt[bh][d][s] = X[b*S+s][h*64+d]  (per-head transpose, bf16) -------
__global__ __launch_bounds__(256) void transpose_head(const u16* __restrict__ X, u16* __restrict__ Xt) {
    __shared__ u16 tile[64 * 65];
    const int t = threadIdx.x;
    const int bh = blockIdx.y, b = bh >> 4, h = bh & 15;
    const int s0 = blockIdx.x << 6;
#pragma unroll
    for (int i = 0; i < 16; ++i) {
        int idx = t + (i << 8);
        int s = idx >> 6, d = idx & 63;
        tile[s * 65 + d] = X[(size_t)(b * S_ + s0 + s) * D_ + h * DH_ + d];
    }
    __syncthreads();
#pragma unroll
    for (int i = 0; i < 16; ++i) {
        int idx = t + (i << 8);
        int d = idx >> 6, s = idx & 63;
        Xt[((size_t)bh * DH_ + d) * S_ + s0 + s] = tile[s * 65 + d];
    }
}

// ------- C[M,N] = A[M,K] @ Bt[N,K]^T + bias; fp32 acc, bf16 MFMA -------
template <bool AF32, bool OUTF32>
__global__ __launch_bounds__(256) void gemm_nt_bias(const void* __restrict__ Ap, const u16* __restrict__ Bt,
                                                    const float* __restrict__ bias, void* __restrict__ Cp,
                                                    int M, int N, int K) {
    __shared__ __align__(16) u16 As[128 * 40];  // stride 40 bf16 = 80B (16B-aligned rows)
    __shared__ __align__(16) u16 Bs[128 * 40];
    const int t = threadIdx.x;
    const int m0 = blockIdx.y * 128, n0 = blockIdx.x * 128;
    const int w = t >> 6, lane = t & 63;
    const int lr = lane & 15, lg = lane >> 4;
    const int wm = (w >> 1) * 64, wn = (w & 1) * 64;
    floatx4 acc[4][4] = {};

    for (int k0 = 0; k0 < K; k0 += 32) {
#pragma unroll
        for (int c = 0; c < 2; ++c) {
            int idx = t + c * 256;
            int row = idx >> 2, k8 = (idx & 3) << 3;
            *(uint4*)&Bs[row * 40 + k8] = *(const uint4*)&Bt[(size_t)(n0 + row) * K + k0 + k8];
        }
        if (AF32) {
            const float* A = (const float*)Ap;
#pragma unroll
            for (int c = 0; c < 4; ++c) {
                int idx = t + c * 256;
                int row = idx >> 3, k4 = (idx & 7) << 2;
                float4 v = *(const float4*)&A[(size_t)(m0 + row) * K + k0 + k4];
                shortx4 hv;
                hv[0] = (short)f2bf(v.x); hv[1] = (short)f2bf(v.y);
                hv[2] = (short)f2bf(v.z); hv[3] = (short)f2bf(v.w);
                *(shortx4*)&As[row * 40 + k4] = hv;
            }
        } else {
            const u16* A = (const u16*)Ap;
#pragma unroll
            for (int c = 0; c < 2; ++c) {
                int idx = t + c * 256;
                int row = idx >> 2, k8 = (idx & 3) << 3;
                *(uint4*)&As[row * 40 + k8] = *(const uint4*)&A[(size_t)(m0 + row) * K + k0 + k8];
            }
        }
        __syncthreads();
        short8 af[4], bfr[4];
#pragma unroll
        for (int i = 0; i < 4; ++i) af[i]  = *(const short8*)&As[(wm + i * 16 + lr) * 40 + lg * 8];
#pragma unroll
        for (int j = 0; j < 4; ++j) bfr[j] = *(const short8*)&Bs[(wn + j * 16 + lr) * 40 + lg * 8];
#pragma unroll
        for (int i = 0; i < 4; ++i)
#pragma unroll
            for (int j = 0; j < 4; ++j)
                acc[i][j] = __builtin_amdgcn_mfma_f32_16x16x32_bf16(af[i], bfr[j], acc[i][j], 0, 0, 0);
        __syncthreads();
    }

#pragma unroll
    for (int j = 0; j < 4; ++j) {
        int col = n0 + wn + j * 16 + lr;
        float bv = bias[col];
#pragma unroll
        for (int i = 0; i < 4; ++i) {
            int rb = m0 + wm + i * 16 + lg * 4;
#pragma unroll
            for (int ii = 0; ii < 4; ++ii) {
                float val = acc[i][j][ii] + bv;
                if (OUTF32) ((float*)Cp)[(size_t)(rb + ii) * N + col] = val;
                else        ((u16*)Cp)[(size_t)(rb + ii) * N + col] = f2bf(val);
            }
        }
    }
}

// ---------------- MFMA flash attention ----------------
// Block: one (b,h), TWO 64-query tiles (jp and 31-jp) for perfect causal balance.
// 4 waves x 16 q-rows. K-tile [key][d] staged natural (B^T layout); V^T staged from Vt.
// P goes C-layout -> LDS(bf16) -> A-layout (m120 pattern).
__global__ __launch_bounds__(256) void attn_mfma(const u16* __restrict__ Q, const u16* __restrict__ K,
                                                 const u16* __restrict__ Vt, u16* __restrict__ O) {
    __shared__ __align__(16) u16 Ks[64 * 72];      // [key][d], stride 72 (144B rows, 16B-aligned)
    __shared__ __align__(16) u16 Vs[64 * 72];      // [d][key]
    __shared__ __align__(16) u16 Ps[4 * 16 * 72];  // per-wave P [q][key]
    const int t = threadIdx.x, w = t >> 6, lane = t & 63;
    const int lr = lane & 15, lg = lane >> 4;
    const int bh = blockIdx.y, b = bh >> 4, h = bh & 15;
    const int jp = blockIdx.x;  // 0..15

    const u16* Kb  = K + (size_t)b * S_ * D_ + h * DH_;   // row stride D_
    const u16* Vtb = Vt + (size_t)bh * DH_ * S_;          // row stride S_
    u16* Pw = Ps + w * (16 * 72);

    for (int pass = 0; pass < 2; ++pass) {
        const int qt = pass ? (31 - jp) : jp;
        const int q0 = qt << 6;

        short8 qf[2];  // Q A-frags, held all block: A[m=lr][k=ks*32+lg*8+j]
#pragma unroll
        for (int ks = 0; ks < 2; ++ks)
            qf[ks] = *(const short8*)&Q[(size_t)(b * S_ + q0 + w * 16 + lr) * D_ + h * DH_ + ks * 32 + lg * 8];

        floatx4 of[4] = {};  // O [16q][64d], C-layout: row=lg*4+ii, col=j*16+lr
        float mrow[4] = {-1e30f, -1e30f, -1e30f, -1e30f};
        float lrow[4] = {0.f, 0.f, 0.f, 0.f};

        const int nkb = qt + 1;
        for (int kb = 0; kb < nkb; ++kb) {
            const int K0 = kb << 6;
#pragma unroll
            for (int c = 0; c < 2; ++c) {  // stage K-tile + V^T-tile (each 64x64)
                int idx = t + (c << 8);
                int row = idx >> 3, c8 = (idx & 7) << 3;
                *(uint4*)&Ks[row * 72 + c8] = *(const uint4*)&Kb[(size_t)(K0 + row) * D_ + c8];
                *(uint4*)&Vs[row * 72 + c8] = *(const uint4*)&Vtb[(size_t)row * S_ + K0 + c8];
            }
            __syncthreads();

            floatx4 sf[4] = {};  // S [16q][64keys]
#pragma unroll
            for (int ks = 0; ks < 2; ++ks)
#pragma unroll
                for (int j = 0; j < 4; ++j) {
                    short8 kf = *(const short8*)&Ks[(j * 16 + lr) * 72 + ks * 32 + lg * 8];
                    sf[j] = __builtin_amdgcn_mfma_f32_16x16x32_bf16(qf[ks], kf, sf[j], 0, 0, 0);
                }

            // softmax (row r = lg*4+ii; cols spread over 16 lanes x 4 tiles)
            float p[4][4];
            const bool diag = (kb == qt);
#pragma unroll
            for (int j = 0; j < 4; ++j)
#pragma unroll
                for (int ii = 0; ii < 4; ++ii) {
                    float v = sf[j][ii] * 0.125f;  // 1/sqrt(64)
                    if (diag && (j * 16 + lr > w * 16 + lg * 4 + ii)) v = -1e30f;
                    p[j][ii] = v;
                }
            float alpha[4], sm[4];
#pragma unroll
            for (int ii = 0; ii < 4; ++ii) {
                float mx = fmaxf(fmaxf(p[0][ii], p[1][ii]), fmaxf(p[2][ii], p[3][ii]));
#pragma unroll
                for (int off = 1; off < 16; off <<= 1) mx = fmaxf(mx, __shfl_xor(mx, off));
                float mn = fmaxf(mrow[ii], mx);
                alpha[ii] = __expf(mrow[ii] - mn);
                mrow[ii] = mn;
                sm[ii] = 0.f;
            }
#pragma unroll
            for (int j = 0; j < 4; ++j)
#pragma unroll
                for (int ii = 0; ii < 4; ++ii) {
                    float e = __expf(p[j][ii] - mrow[ii]);
                    p[j][ii] = e;
                    sm[ii] += e;
                }
#pragma unroll
            for (int ii = 0; ii < 4; ++ii) {
#pragma unroll
                for (int off = 1; off < 16; off <<= 1) sm[ii] += __shfl_xor(sm[ii], off);
                lrow[ii] = lrow[ii] * alpha[ii] + sm[ii];
            }
#pragma unroll
            for (int j = 0; j < 4; ++j)
#pragma unroll
                for (int ii = 0; ii < 4; ++ii) {
                    of[j][ii] *= alpha[ii];
                    Pw[(lg * 4 + ii) * 72 + j * 16 + lr] = f2bf(p[j][ii]);  // C->LDS
                }

            short8 pa[2];  // P A-frags: A[m=lr][k=ks*32+lg*8+j]
#pragma unroll
            for (int ks = 0; ks < 2; ++ks)
                pa[ks] = *(const short8*)&Pw[lr * 72 + ks * 32 + lg * 8];
#pragma unroll
            for (int ks = 0; ks < 2; ++ks)
#pragma unroll
                for (int j = 0; j < 4; ++j) {
                    short8 vf = *(const short8*)&Vs[(j * 16 + lr) * 72 + ks * 32 + lg * 8];
                    of[j] = __builtin_amdgcn_mfma_f32_16x16x32_bf16(pa[ks], vf, of[j], 0, 0, 0);
                }
            __syncthreads();
        }
#pragma unroll
        for (int j = 0; j < 4; ++j)
#pragma unroll
            for (int ii = 0; ii < 4; ++ii)
                O[(size_t)(b * S_ + q0 + w * 16 + lg * 4 + ii) * D_ + h * DH_ + j * 16 + lr] =
                    f2bf(of[j][ii] / lrow[ii]);
    }
}

extern "C" void kernel_launch(void* const* d_in, const int* in_sizes, int n_in,
                              void* d_out, int out_size, void* d_ws, size_t ws_size,
                              hipStream_t stream) {
    (void)in_sizes; (void)n_in; (void)out_size; (void)ws_size;
    const float* x  = (const float*)d_in[0];
    const float* Wq = (const float*)d_in[1];
    const float* bq = (const float*)d_in[2];
    const float* Wk = (const float*)d_in[3];
    const float* bk = (const float*)d_in[4];
    const float* Wv = (const float*)d_in[5];
    const float* bv = (const float*)d_in[6];
    const float* Wo = (const float*)d_in[7];
    const float* bo = (const float*)d_in[8];

    // ws layout (u16 elems): 4x Wt (1M) | Q (4M) | K (4M) | V (4M) | Vt (4M) | attn (4M) = 48 MB
    u16* ws  = (u16*)d_ws;
    u16* Wtq = ws + (size_t)0 * (1 << 20);
    u16* Wtk = ws + (size_t)1 * (1 << 20);
    u16* Wtv = ws + (size_t)2 * (1 << 20);
    u16* Wto = ws + (size_t)3 * (1 << 20);
    u16* Qm  = ws + (size_t)4 * (1 << 20);
    u16* Km  = ws + (size_t)8 * (1 << 20);
    u16* Vm  = ws + (size_t)12 * (1 << 20);
    u16* Vtm = ws + (size_t)16 * (1 << 20);
    u16* Am  = ws + (size_t)20 * (1 << 20);

    dim3 tw_grid(32, 32), tw_blk(32, 8);
    transpose_w<<<tw_grid, tw_blk, 0, stream>>>(Wq, Wtq);
    transpose_w<<<tw_grid, tw_blk, 0, stream>>>(Wk, Wtk);
    transpose_w<<<tw_grid, tw_blk, 0, stream>>>(Wv, Wtv);
    transpose_w<<<tw_grid, tw_blk, 0, stream>>>(Wo, Wto);

    dim3 g_grid(1024 / 128, 4096 / 128);  // (N/128, M/128)
    gemm_nt_bias<true, false><<<g_grid, 256, 0, stream>>>(x, Wtq, bq, Qm, 4096, 1024, 1024);
    gemm_nt_bias<true, false><<<g_grid, 256, 0, stream>>>(x, Wtk, bk, Km, 4096, 1024, 1024);
    gemm_nt_bias<true, false><<<g_grid, 256, 0, stream>>>(x, Wtv, bv, Vm, 4096, 1024, 1024);

    transpose_head<<<dim3(32, 32), 256, 0, stream>>>(Vm, Vtm);

    attn_mfma<<<dim3(16, 32), 256, 0, stream>>>(Qm, Km, Vtm, Am);

    gemm_nt_bias<false, true><<<g_grid, 256, 0, stream>>>(Am, Wto, bo, d_out, 4096, 1024, 1024);
}

// Round 5
// 242.300 us; speedup vs baseline: 5.1562x; 1.3736x over previous
//
#include <hip/hip_runtime.h>

typedef unsigned short u16;
typedef __attribute__((ext_vector_type(8))) short short8;   // 8 bf16 (4 VGPRs) MFMA A/B frag
typedef __attribute__((ext_vector_type(4))) short shortx4;  // 4 bf16 (8B)
typedef __attribute__((ext_vector_type(4))) float floatx4;  // MFMA C/D frag

#define S_ 2048
#define D_ 1024
#define DQKV_ 3072
#define H_ 16
#define DH_ 64

#define EXP2F(x) __builtin_amdgcn_exp2f(x)

__device__ __forceinline__ float bf2f(u16 x) {
    union { unsigned int u; float f; } v; v.u = ((unsigned int)x) << 16; return v.f;
}
__device__ __forceinline__ u16 f2bf(float f) {  // RNE
    unsigned int u = __float_as_uint(f);
    return (u16)((u + 0x7fffu + ((u >> 16) & 1u)) >> 16);
}
__device__ __forceinline__ u16 f2bf_fast(float f) {  // round-to-nearest (ties up) — P is in (0,1], fine
    return (u16)((__float_as_uint(f) + 0x8000u) >> 16);
}

// ---------------- xb = bf16(x), 4096x1024 ----------------
__global__ __launch_bounds__(256) void convert_x(const float* __restrict__ x, u16* __restrict__ xb) {
    const size_t i = ((size_t)blockIdx.x * 256 + threadIdx.x) * 4;
    float4 v = *(const float4*)&x[i];
    shortx4 h;
    h[0] = (short)f2bf(v.x); h[1] = (short)f2bf(v.y);
    h[2] = (short)f2bf(v.z); h[3] = (short)f2bf(v.w);
    *(shortx4*)&xb[i] = h;
}

// ------- fused W transposes: WqkvT[3072][1024] (=[Wq^T;Wk^T;Wv^T]) and WoT[1024][1024] -------
__global__ __launch_bounds__(256) void transpose_w4(const float* __restrict__ Wq, const float* __restrict__ Wk,
                                                    const float* __restrict__ Wv, const float* __restrict__ Wo,
                                                    u16* __restrict__ Wqkvt, u16* __restrict__ Wot) {
    __shared__ u16 tile[32][33];
    const int z = blockIdx.z;
    const float* W = (z == 0) ? Wq : (z == 1) ? Wk : (z == 2) ? Wv : Wo;
    u16* dst = (z == 3) ? Wot : (Wqkvt + (size_t)z * D_ * D_);
    const int tx = threadIdx.x, ty = threadIdx.y;
    const int n0 = blockIdx.x * 32, k0 = blockIdx.y * 32;
#pragma unroll
    for (int r = 0; r < 4; ++r) {
        int k = ty + r * 8;
        tile[k][tx] = f2bf(W[(size_t)(k0 + k) * D_ + n0 + tx]);
    }
    __syncthreads();
#pragma unroll
    for (int r = 0; r < 4; ++r) {
        int n = ty + r * 8;
        dst[(size_t)(n0 + n) * D_ + k0 + tx] = tile[tx][n];
    }
}

// ------- Vt[bh][d][s] = QKV[b*S+s][2048 + h*64 + d]  (per-head V transpose) -------
__global__ __launch_bounds__(256) void transpose_headV(const u16* __restrict__ QKV, u16* __restrict__ Vt) {
    __shared__ u16 tile[64 * 65];
    const int t = threadIdx.x;
    const int bh = blockIdx.y, b = bh >> 4, h = bh & 15;
    const int s0 = blockIdx.x << 6;
#pragma unroll
    for (int i = 0; i < 16; ++i) {
        int idx = t + (i << 8);
        int s = idx >> 6, d = idx & 63;
        tile[s * 65 + d] = QKV[(size_t)(b * S_ + s0 + s) * DQKV_ + 2048 + h * DH_ + d];
    }
    __syncthreads();
#pragma unroll
    for (int i = 0; i < 16; ++i) {
        int idx = t + (i << 8);
        int d = idx >> 6, s = idx & 63;
        Vt[((size_t)bh * DH_ + d) * S_ + s0 + s] = tile[s * 65 + d];
    }
}

// ------- C[M,N] = A[M,K] @ Bt[N,K]^T + bias; bf16 in, fp32 acc -------
// BMxBN tile, 4 waves in 2x2 grid, each (BM/2)x(BN/2). Bias selected per-1024-col segment.
template <int BM, int BN, bool OUTF32>
__global__ __launch_bounds__(256) void gemm_bt(const u16* __restrict__ A, const u16* __restrict__ Bt,
                                               const float* __restrict__ b0, const float* __restrict__ b1,
                                               const float* __restrict__ b2, void* __restrict__ Cp,
                                               int M, int N, int Kd) {
    constexpr int FI = BM / 32, FJ = BN / 32;
    __shared__ __align__(16) u16 As[BM * 40];
    __shared__ __align__(16) u16 Bs[BN * 40];
    const int t = threadIdx.x;
    const int m0 = blockIdx.y * BM, n0 = blockIdx.x * BN;
    const int w = t >> 6, lane = t & 63;
    const int lr = lane & 15, lg = lane >> 4;
    const int wm = (w >> 1) * (BM / 2), wn = (w & 1) * (BN / 2);
    floatx4 acc[FI][FJ] = {};

    for (int k0 = 0; k0 < Kd; k0 += 32) {
#pragma unroll
        for (int c = 0; c < BM / 64; ++c) {
            int idx = t + c * 256;
            int row = idx >> 2, k8 = (idx & 3) << 3;
            *(uint4*)&As[row * 40 + k8] = *(const uint4*)&A[(size_t)(m0 + row) * Kd + k0 + k8];
        }
#pragma unroll
        for (int c = 0; c < BN / 64; ++c) {
            int idx = t + c * 256;
            int row = idx >> 2, k8 = (idx & 3) << 3;
            *(uint4*)&Bs[row * 40 + k8] = *(const uint4*)&Bt[(size_t)(n0 + row) * Kd + k0 + k8];
        }
        __syncthreads();
        short8 af[FI], bfr[FJ];
#pragma unroll
        for (int i = 0; i < FI; ++i) af[i]  = *(const short8*)&As[(wm + i * 16 + lr) * 40 + lg * 8];
#pragma unroll
        for (int j = 0; j < FJ; ++j) bfr[j] = *(const short8*)&Bs[(wn + j * 16 + lr) * 40 + lg * 8];
#pragma unroll
        for (int i = 0; i < FI; ++i)
#pragma unroll
            for (int j = 0; j < FJ; ++j)
                acc[i][j] = __builtin_amdgcn_mfma_f32_16x16x32_bf16(af[i], bfr[j], acc[i][j], 0, 0, 0);
        __syncthreads();
    }

#pragma unroll
    for (int j = 0; j < FJ; ++j) {
        int col = n0 + wn + j * 16 + lr;
        const float* bp = (col < 1024) ? b0 : (col < 2048) ? b1 : b2;
        float bv = bp[col & 1023];
#pragma unroll
        for (int i = 0; i < FI; ++i) {
            int rb = m0 + wm + i * 16 + lg * 4;
#pragma unroll
            for (int ii = 0; ii < 4; ++ii) {
                float val = acc[i][j][ii] + bv;
                if (OUTF32) ((float*)Cp)[(size_t)(rb + ii) * N + col] = val;
                else        ((u16*)Cp)[(size_t)(rb + ii) * N + col] = f2bf(val);
            }
        }
    }
}

// ---------------- MFMA flash attention, single 64-q tile per block ----------------
// grid (bh=32, qidx=32); qt = 31-qidx so heavy tiles dispatch first (LPT).
// 4 waves x 16 q-rows share K/V LDS tiles. Softmax in exp2 domain.
__global__ __launch_bounds__(256) void attn_mfma(const u16* __restrict__ QKV, const u16* __restrict__ Vt,
                                                 u16* __restrict__ O) {
    __shared__ __align__(16) u16 Ks[64 * 72];      // [key][d] (B^T layout), 144B rows
    __shared__ __align__(16) u16 Vs[64 * 72];      // [d][key]
    __shared__ __align__(16) u16 Ps[4 * 16 * 76];  // per-wave P [q][key], stride 76: conflict-free b16 scatter
    const int t = threadIdx.x, w = t >> 6, lane = t & 63;
    const int lr = lane & 15, lg = lane >> 4;
    const int bh = blockIdx.x, b = bh >> 4, h = bh & 15;
    const int qt = 31 - blockIdx.y;
    const int q0 = qt << 6;
    const float cs = 0.18033688f;  // (1/sqrt(64)) * log2(e)

    const u16* Kb  = QKV + (size_t)b * S_ * DQKV_ + 1024 + h * DH_;  // row stride DQKV_
    const u16* Vtb = Vt + (size_t)bh * DH_ * S_;                     // row stride S_
    u16* Pw = Ps + w * (16 * 76);

    short8 qf[2];  // Q A-frags: A[m=lr][k=ks*32+lg*8+j]
#pragma unroll
    for (int ks = 0; ks < 2; ++ks)
        qf[ks] = *(const short8*)&QKV[(size_t)(b * S_ + q0 + w * 16 + lr) * DQKV_ + h * DH_ + ks * 32 + lg * 8];

    floatx4 of[4] = {};  // O [16q][64d] C-layout: row=lg*4+ii, col=j*16+lr
    float mrow[4] = {-1e30f, -1e30f, -1e30f, -1e30f};
    float lrow[4] = {0.f, 0.f, 0.f, 0.f};

    for (int kb = 0; kb <= qt; ++kb) {
        const int K0 = kb << 6;
#pragma unroll
        for (int c = 0; c < 2; ++c) {  // stage K-tile + V^T-tile
            int idx = t + (c << 8);
            int row = idx >> 3, c8 = (idx & 7) << 3;
            *(uint4*)&Ks[row * 72 + c8] = *(const uint4*)&Kb[(size_t)(K0 + row) * DQKV_ + c8];
            *(uint4*)&Vs[row * 72 + c8] = *(const uint4*)&Vtb[(size_t)row * S_ + K0 + c8];
        }
        __syncthreads();

        floatx4 sf[4] = {};  // S [16q][64keys]
#pragma unroll
        for (int ks = 0; ks < 2; ++ks)
#pragma unroll
            for (int j = 0; j < 4; ++j) {
                short8 kf = *(const short8*)&Ks[(j * 16 + lr) * 72 + ks * 32 + lg * 8];
                sf[j] = __builtin_amdgcn_mfma_f32_16x16x32_bf16(qf[ks], kf, sf[j], 0, 0, 0);
            }

        float p[4][4];
        const bool diag = (kb == qt);
#pragma unroll
        for (int j = 0; j < 4; ++j)
#pragma unroll
            for (int ii = 0; ii < 4; ++ii) {
                float v = sf[j][ii] * cs;  // exp2 domain
                if (diag && (j * 16 + lr > w * 16 + lg * 4 + ii)) v = -1e30f;
                p[j][ii] = v;
            }
        float alpha[4], sm[4];
#pragma unroll
        for (int ii = 0; ii < 4; ++ii) {
            float mx = fmaxf(fmaxf(p[0][ii], p[1][ii]), fmaxf(p[2][ii], p[3][ii]));
#pragma unroll
            for (int off = 1; off < 16; off <<= 1) mx = fmaxf(mx, __shfl_xor(mx, off));
            float mn = fmaxf(mrow[ii], mx);
            alpha[ii] = EXP2F(mrow[ii] - mn);
            mrow[ii] = mn;
            sm[ii] = 0.f;
        }
#pragma unroll
        for (int j = 0; j < 4; ++j)
#pragma unroll
            for (int ii = 0; ii < 4; ++ii) {
                float e = EXP2F(p[j][ii] - mrow[ii]);
                p[j][ii] = e;
                sm[ii] += e;
            }
#pragma unroll
        for (int ii = 0; ii < 4; ++ii) {
#pragma unroll
            for (int off = 1; off < 16; off <<= 1) sm[ii] += __shfl_xor(sm[ii], off);
            lrow[ii] = lrow[ii] * alpha[ii] + sm[ii];
        }
#pragma unroll
        for (int j = 0; j < 4; ++j)
#pragma unroll
            for (int ii = 0; ii < 4; ++ii) {
                of[j][ii] *= alpha[ii];
                Pw[(lg * 4 + ii) * 76 + j * 16 + lr] = f2bf_fast(p[j][ii]);  // C->LDS
            }

#pragma unroll
        for (int ks = 0; ks < 2; ++ks) {
            // P A-frag: two 8B reads (stride-76 rows are 8B-aligned, not 16B)
            union { short8 v; shortx4 h[2]; } pa;
            pa.h[0] = *(const shortx4*)&Pw[lr * 76 + ks * 32 + lg * 8];
            pa.h[1] = *(const shortx4*)&Pw[lr * 76 + ks * 32 + lg * 8 + 4];
#pragma unroll
            for (int j = 0; j < 4; ++j) {
                short8 vf = *(const short8*)&Vs[(j * 16 + lr) * 72 + ks * 32 + lg * 8];
                of[j] = __builtin_amdgcn_mfma_f32_16x16x32_bf16(pa.v, vf, of[j], 0, 0, 0);
            }
        }
        __syncthreads();
    }
#pragma unroll
    for (int j = 0; j < 4; ++j)
#pragma unroll
        for (int ii = 0; ii < 4; ++ii)
            O[(size_t)(b * S_ + q0 + w * 16 + lg * 4 + ii) * D_ + h * DH_ + j * 16 + lr] =
                f2bf(of[j][ii] / lrow[ii]);
}

extern "C" void kernel_launch(void* const* d_in, const int* in_sizes, int n_in,
                              void* d_out, int out_size, void* d_ws, size_t ws_size,
                              hipStream_t stream) {
    (void)in_sizes; (void)n_in; (void)out_size; (void)ws_size;
    const float* x  = (const float*)d_in[0];
    const float* Wq = (const float*)d_in[1];
    const float* bq = (const float*)d_in[2];
    const float* Wk = (const float*)d_in[3];
    const float* bk = (const float*)d_in[4];
    const float* Wv = (const float*)d_in[5];
    const float* bv = (const float*)d_in[6];
    const float* Wo = (const float*)d_in[7];
    const float* bo = (const float*)d_in[8];

    // ws layout (u16 elems), 48 MB total:
    //   [0,3M)   WqkvT   [3M,4M) WoT   [4M,16M) QKV   [16M,20M) Vt
    //   [20M,24M) xbf (dead after QKV gemm) -> reused as Am (attention out)
    u16* ws    = (u16*)d_ws;
    u16* WqkvT = ws;
    u16* WoT   = ws + (size_t)3 * (1 << 20);
    u16* QKV   = ws + (size_t)4 * (1 << 20);
    u16* Vtm   = ws + (size_t)16 * (1 << 20);
    u16* xbf   = ws + (size_t)20 * (1 << 20);
    u16* Am    = ws + (size_t)20 * (1 << 20);

    convert_x<<<4096, 256, 0, stream>>>(x, xbf);
    transpose_w4<<<dim3(32, 32, 4), dim3(32, 8), 0, stream>>>(Wq, Wk, Wv, Wo, WqkvT, WoT);

    // QKV = xbf @ WqkvT^T + [bq|bk|bv]  (M=4096, N=3072)
    gemm_bt<128, 128, false><<<dim3(DQKV_ / 128, 4096 / 128), 256, 0, stream>>>(
        xbf, WqkvT, bq, bk, bv, QKV, 4096, DQKV_, 1024);

    transpose_headV<<<dim3(32, 32), 256, 0, stream>>>(QKV, Vtm);

    attn_mfma<<<dim3(32, 32), 256, 0, stream>>>(QKV, Vtm, Am);

    // out = Am @ WoT^T + bo  (M=4096, N=1024), fp32 out
    gemm_bt<64, 128, true><<<dim3(1024 / 128, 4096 / 64), 256, 0, stream>>>(
        Am, WoT, bo, bo, bo, d_out, 4096, 1024, 1024);
}